// Round 4
// baseline (584.420 us; speedup 1.0000x reference)
//
#include <hip/hip_runtime.h>
#include <math.h>

#define N_TOK   16384
#define K_TOT   (8 * N_TOK)      // 131072 reduction rows per batch
#define N_BATCH 4
#define BPB     128              // K1 blocks per batch
#define RPB     (K_TOT / BPB)    // 1024 contiguous rows per block

// ---------------------------------------------------------------------------
// K1 (round 4): register-only fp32 outer-product stream.
//   part[blk][c][d] = sum_{tok in block} K[tok][c] * V[tok][d]
// Round-3 post-mortem: WRITE_SIZE=200MB @ VGPR=128 cap -> scratch spills from
// the unroll-32 LDS-broadcast scheme; and the 4x4-tile LDS reads (8 floats /
// thread / token) made the LDS pipe the ~80us floor anyway. This version has
// NO LDS, NO barriers, NO transpose:
//   - lane c = laneid:  K[tok][lane] is one coalesced 256B load per wave-token
//   - V[tok][d0..d0+7] is wave-uniform -> two uniform-address dwordx4 loads
//     (single broadcast transaction; result in VGPRs, valid FMA operands)
//   - 8 v_fmac_f32 into acc[8]; 8 waves x 8 d-octets cover the 64x64 tile;
//     each wave walks all 1024 tokens of the block independently.
// Per-CU: FMA 65K cy, HBM 268MB/256CU = 42.5us floor, L1 serves the 8x
// K-row re-read (L2 backstops wave drift). Unroll 8 only (~70 VGPR in
// flight) to stay far from the spill cliff.
// ---------------------------------------------------------------------------
__global__ __launch_bounds__(512, 2) void k1_outer(
    const float* __restrict__ key, const float* __restrict__ val,
    float* __restrict__ part) {
  int blk  = blockIdx.x;
  int b    = blk / BPB;
  int p    = blk % BPB;
  int t    = threadIdx.x;
  int wave = t >> 6;
  int lane = t & 63;

  size_t base = ((size_t)b * K_TOT + (size_t)p * RPB) * 64;  // float index
  const float* Kp = key + base + lane;        // K[tok][lane]
  const float* Vp = val + base + wave * 8;    // V[tok][wave*8 ..]

  float acc[8];
#pragma unroll
  for (int j = 0; j < 8; j++) acc[j] = 0.f;

  for (int tk = 0; tk < RPB; tk += 8) {
#pragma unroll
    for (int u = 0; u < 8; u++) {
      size_t o = (size_t)(tk + u) * 64;
      float  kk = Kp[o];
      float4 v0 = *(const float4*)&Vp[o];
      float4 v1 = *(const float4*)&Vp[o + 4];
      acc[0] = fmaf(kk, v0.x, acc[0]);
      acc[1] = fmaf(kk, v0.y, acc[1]);
      acc[2] = fmaf(kk, v0.z, acc[2]);
      acc[3] = fmaf(kk, v0.w, acc[3]);
      acc[4] = fmaf(kk, v1.x, acc[4]);
      acc[5] = fmaf(kk, v1.y, acc[5]);
      acc[6] = fmaf(kk, v1.z, acc[6]);
      acc[7] = fmaf(kk, v1.w, acc[7]);
    }
  }

  float* dst = part + (size_t)blk * 4096 + lane * 64 + wave * 8;
  *(float4*)dst       = make_float4(acc[0], acc[1], acc[2], acc[3]);
  *(float4*)(dst + 4) = make_float4(acc[4], acc[5], acc[6], acc[7]);
}

// ---------------------------------------------------------------------------
// K2: reduce 128 partial tiles per batch -> kv[b][c][d].
// ---------------------------------------------------------------------------
__global__ __launch_bounds__(256, 4) void k2_reduce(
    const float* __restrict__ part, float* __restrict__ kv, int bpb) {
  int b  = blockIdx.x >> 6;
  int c  = blockIdx.x & 63;
  int p4 = threadIdx.x >> 6;
  int d  = threadIdx.x & 63;

  float s = 0.f;
  int iters = bpb >> 2;
  const float* src = part + (size_t)(b * bpb) * 4096 + c * 64 + d;
#pragma unroll 4
  for (int x = 0; x < iters; x++) s += src[(size_t)(p4 + 4 * x) * 4096];

  __shared__ float l[256];
  l[threadIdx.x] = s;
  __syncthreads();
  if (p4 == 0)
    kv[((size_t)b * 64 + c) * 64 + d] = l[d] + l[64 + d] + l[128 + d] + l[192 + d];
}

// ---------------------------------------------------------------------------
// K3: fused softmax + out (verified rounds 2-3).
//   e[c][d]   = exp(kv[b][c][d] - max_c kv[b][:,d])   (unnormalized)
//   out[b,m,d]= (alpha/den[d]) * sum_c key_cur[b,m,c]*e[c][d] + val_cur[b,m,d]
// ---------------------------------------------------------------------------
__global__ __launch_bounds__(256, 4) void k3_out(
    const float* __restrict__ kv, const float* __restrict__ keyc,
    const float* __restrict__ valc, const float* __restrict__ alphap,
    float* __restrict__ out) {
  __shared__ float Ps[4096];       // e = exp(kv - mx[d])
  __shared__ float kT[64 * 68];
  __shared__ float redm[4][64];    // per-group partial max over c
  __shared__ float reds[4][64];    // per-group partial sum of e over c

  int bb = blockIdx.x >> 8;
  int mb = blockIdx.x & 255;
  int m0 = mb * 64;
  int t = threadIdx.x;

  // softmax role: thread (cg, d) reduces c = cg*16 .. cg*16+15 of column d
  int d  = t & 63;
  int cg = t >> 6;
  const float* kvb = kv + (size_t)bb * 4096;
  float v[16];
  float mx = -3.0e38f;
#pragma unroll
  for (int i = 0; i < 16; i++) {
    v[i] = kvb[(cg * 16 + i) * 64 + d];
    mx = fmaxf(mx, v[i]);
  }
  redm[cg][d] = mx;

  // kT staging (independent of softmax; same barrier covers both)
  int r  = t >> 2;
  int cb = (t & 3) * 16;
  const float* krow = keyc + ((size_t)bb * N_TOK + m0 + r) * 64;
#pragma unroll
  for (int u = 0; u < 4; u++) {
    float4 kk = *(const float4*)&krow[cb + 4 * u];
    int c = cb + 4 * u;
    kT[(c + 0) * 68 + r] = kk.x;
    kT[(c + 1) * 68 + r] = kk.y;
    kT[(c + 2) * 68 + r] = kk.z;
    kT[(c + 3) * 68 + r] = kk.w;
  }
  __syncthreads();

  mx = fmaxf(fmaxf(redm[0][d], redm[1][d]), fmaxf(redm[2][d], redm[3][d]));
  float s = 0.f;
#pragma unroll
  for (int i = 0; i < 16; i++) {
    float e = __expf(v[i] - mx);
    Ps[(cg * 16 + i) * 64 + d] = e;
    s += e;
  }
  reds[cg][d] = s;
  __syncthreads();

  int wave = t >> 6, lane = t & 63;
  int mi = lane >> 3, j = lane & 7;
  int m = wave * 16 + mi * 2;

  float acc[2][8];
#pragma unroll
  for (int a = 0; a < 2; a++)
#pragma unroll
    for (int dd = 0; dd < 8; dd++) acc[a][dd] = 0.f;

#pragma unroll 4
  for (int c = 0; c < 64; c++) {
    float2 kk = *(const float2*)&kT[c * 68 + m];
    float4 p0 = *(const float4*)&Ps[c * 64 + 8 * j];
    float4 p1 = *(const float4*)&Ps[c * 64 + 8 * j + 4];
    float pr[8] = {p0.x, p0.y, p0.z, p0.w, p1.x, p1.y, p1.z, p1.w};
#pragma unroll
    for (int dd = 0; dd < 8; dd++) {
      acc[0][dd] = fmaf(kk.x, pr[dd], acc[0][dd]);
      acc[1][dd] = fmaf(kk.y, pr[dd], acc[1][dd]);
    }
  }

  float alpha = alphap[0];
  float sc[8];
#pragma unroll
  for (int dd = 0; dd < 8; dd++) {
    int dq = 8 * j + dd;
    float den = reds[0][dq] + reds[1][dq] + reds[2][dq] + reds[3][dq];
    sc[dd] = alpha / den;
  }

#pragma unroll
  for (int a = 0; a < 2; a++) {
    size_t off = ((size_t)bb * N_TOK + m0 + m + a) * 64 + 8 * j;
    float4 v0 = *(const float4*)&valc[off];
    float4 v1 = *(const float4*)&valc[off + 4];
    float4 o0 = make_float4(fmaf(sc[0], acc[a][0], v0.x),
                            fmaf(sc[1], acc[a][1], v0.y),
                            fmaf(sc[2], acc[a][2], v0.z),
                            fmaf(sc[3], acc[a][3], v0.w));
    float4 o1 = make_float4(fmaf(sc[4], acc[a][4], v1.x),
                            fmaf(sc[5], acc[a][5], v1.y),
                            fmaf(sc[6], acc[a][6], v1.z),
                            fmaf(sc[7], acc[a][7], v1.w));
    *(float4*)&out[off] = o0;
    *(float4*)&out[off + 4] = o1;
  }
}

// ---------------------------------------------------------------------------
extern "C" void kernel_launch(void* const* d_in, const int* in_sizes, int n_in,
                              void* d_out, int out_size, void* d_ws,
                              size_t ws_size, hipStream_t stream) {
  const float* key_mem = (const float*)d_in[0];
  const float* val_mem = (const float*)d_in[1];
  const float* key_cur = (const float*)d_in[2];
  const float* val_cur = (const float*)d_in[3];
  const float* alpha   = (const float*)d_in[4];
  float* out = (float*)d_out;
  float* ws  = (float*)d_ws;

  float* part = ws;                                    // 512 tiles (8.4 MB)
  float* kv   = ws + (size_t)(N_BATCH * BPB) * 4096;   // 4 tiles

  k1_outer<<<N_BATCH * BPB, 512, 0, stream>>>(key_mem, val_mem, part);
  k2_reduce<<<256, 256, 0, stream>>>(part, kv, BPB);
  k3_out<<<N_BATCH * (N_TOK / 64), 256, 0, stream>>>(kv, key_cur, val_cur,
                                                     alpha, out);
}